// Round 1
// baseline (132.407 us; speedup 1.0000x reference)
//
#include <hip/hip_runtime.h>
#include <hip/hip_bf16.h>
#include <stdint.h>

#define NB 4
#define NS 4096
#define ND 128
#define QBLK 64
#define KVBLK 64
#define NTILES (NS / KVBLK)

typedef __attribute__((ext_vector_type(8))) short short8;
typedef __attribute__((ext_vector_type(4))) float f32x4;

// log2(e) / sqrt(128): folded into Q so scores come out in exp2 domain.
#define QSCALE 0.12751744f

__device__ __forceinline__ unsigned short f2bf(float f) {
  union { float f; uint32_t u; } v; v.f = f;
  uint32_t r = v.u + 0x7FFFu + ((v.u >> 16) & 1u);   // RNE
  return (unsigned short)(r >> 16);
}

__device__ __forceinline__ void gl_lds16(const void* g, void* l) {
  __builtin_amdgcn_global_load_lds(
      (const __attribute__((address_space(1))) uint32_t*)g,
      (__attribute__((address_space(3))) uint32_t*)l, 16, 0, 0);
}

#define MFMA16(a, b, c) __builtin_amdgcn_mfma_f32_16x16x32_bf16((a), (b), (c), 0, 0, 0)

// ---------------------------------------------------------------------------
// Projection: T = x @ W^T + b  (per blockIdx.z: 0=Q,1=K,2=V)
// Q,K -> bf16 [B][S][D] row-major (Q pre-scaled by log2e/sqrt(D));
// V   -> bf16 [B][D][S] (transposed) so attention's PV reads are contiguous.
// ---------------------------------------------------------------------------
__global__ __launch_bounds__(256) void proj_kernel(
    const float* __restrict__ x,
    const float* __restrict__ Wq, const float* __restrict__ bq,
    const float* __restrict__ Wk, const float* __restrict__ bk,
    const float* __restrict__ Wv, const float* __restrict__ bv,
    unsigned short* __restrict__ Qo, unsigned short* __restrict__ Ko,
    unsigned short* __restrict__ Vt)
{
  // Xs occupies first 64*128 elems; V-transpose bounce (128 x 72) overlays it later.
  __shared__ unsigned short XsTt[128 * 72];
  __shared__ unsigned short Ws[128 * 128];

  const int tile  = blockIdx.x;   // 64 tiles of 64 rows
  const int b     = blockIdx.y;
  const int which = blockIdx.z;

  const float* W    = (which == 0) ? Wq : (which == 1) ? Wk : Wv;
  const float* bias = (which == 0) ? bq : (which == 1) ? bk : bv;

  const int t = threadIdx.x;
  const int wave = t >> 6, lane = t & 63;
  const int lr = lane & 15, lg = lane >> 4;

  const float* xb = x + ((size_t)b * NS + (size_t)tile * 64) * ND;

  // ---- stage X tile (64x128 f32 -> bf16, XOR-swizzled rows) ----
#pragma unroll
  for (int c = 0; c < 4; ++c) {
    int eo = (c * 256 + t) * 8;
    int row = eo >> 7, col = eo & 127;
    const float4* s = (const float4*)(xb + row * ND + col);
    float4 v0 = s[0], v1 = s[1];
    short8 o;
    o[0] = f2bf(v0.x); o[1] = f2bf(v0.y); o[2] = f2bf(v0.z); o[3] = f2bf(v0.w);
    o[4] = f2bf(v1.x); o[5] = f2bf(v1.y); o[6] = f2bf(v1.z); o[7] = f2bf(v1.w);
    int ba = (row * 256 + col * 2) ^ ((row & 7) << 4);
    *(short8*)((char*)XsTt + ba) = o;
  }
  // ---- stage W (128x128 f32 -> bf16, swizzled) ----
#pragma unroll
  for (int c = 0; c < 8; ++c) {
    int eo = (c * 256 + t) * 8;
    int row = eo >> 7, col = eo & 127;
    const float4* s = (const float4*)(W + row * ND + col);
    float4 v0 = s[0], v1 = s[1];
    short8 o;
    o[0] = f2bf(v0.x); o[1] = f2bf(v0.y); o[2] = f2bf(v0.z); o[3] = f2bf(v0.w);
    o[4] = f2bf(v1.x); o[5] = f2bf(v1.y); o[6] = f2bf(v1.z); o[7] = f2bf(v1.w);
    int ba = (row * 256 + col * 2) ^ ((row & 7) << 4);
    *(short8*)((char*)Ws + ba) = o;
  }
  __syncthreads();

  // ---- MFMA: each wave computes 16 rows x 128 cols ----
  short8 af[4];
#pragma unroll
  for (int kk = 0; kk < 4; ++kk) {
    int row = wave * 16 + lr;
    int ba = (row * 256 + kk * 64 + lg * 16) ^ ((row & 7) << 4);
    af[kk] = *(const short8*)((const char*)XsTt + ba);
  }
  f32x4 acc[8] = {};
#pragma unroll
  for (int kk = 0; kk < 4; ++kk) {
#pragma unroll
    for (int nf = 0; nf < 8; ++nf) {
      int n = nf * 16 + lr;
      int ba = (n * 256 + kk * 64 + lg * 16) ^ ((n & 7) << 4);
      short8 bf = *(const short8*)((const char*)Ws + ba);
      acc[nf] = MFMA16(af[kk], bf, acc[nf]);
    }
  }

  if (which < 2) {
    unsigned short* Out = (which == 0) ? Qo : Ko;
    const float sc = (which == 0) ? QSCALE : 1.0f;
#pragma unroll
    for (int nf = 0; nf < 8; ++nf) {
      float bb = bias[nf * 16 + lr];
#pragma unroll
      for (int r = 0; r < 4; ++r) {
        float v = (acc[nf][r] + bb) * sc;
        int row = tile * 64 + wave * 16 + lg * 4 + r;
        Out[((size_t)b * NS + row) * ND + nf * 16 + lr] = f2bf(v);
      }
    }
  } else {
    __syncthreads();              // everyone done reading Xs before overlay
    unsigned short* Tt = XsTt;    // [128][72]
#pragma unroll
    for (int nf = 0; nf < 8; ++nf) {
      float bb = bias[nf * 16 + lr];
#pragma unroll
      for (int r = 0; r < 4; ++r) {
        int e = nf * 16 + lr;
        int sl = wave * 16 + lg * 4 + r;
        Tt[e * 72 + sl] = f2bf(acc[nf][r] + bb);
      }
    }
    __syncthreads();
    // coalesced write-out: thread pair per row e, 32 elems each
    int e = t >> 1, off = (t & 1) * 32;
    const short8* src = (const short8*)(Tt + e * 72 + off);
    short8* dst = (short8*)(Vt + ((size_t)b * ND + e) * NS + (size_t)tile * 64 + off);
#pragma unroll
    for (int i = 0; i < 4; ++i) dst[i] = src[i];
  }
}

// ---------------------------------------------------------------------------
// Flash attention: 4 waves x 16 q-rows, KV tiles of 64, double-buffered LDS.
// K staged [64][128] swizzled; V staged from Vt as [128][64] swizzled.
// ---------------------------------------------------------------------------
__global__ __launch_bounds__(256) void attn_kernel(
    const unsigned short* __restrict__ Q, const unsigned short* __restrict__ K,
    const unsigned short* __restrict__ Vt, float* __restrict__ Out)
{
  extern __shared__ char smem[];
  char* ksbase = smem;            // 2 x 16 KB
  char* vsbase = smem + 32768;    // 2 x 16 KB
  char* psbase = smem + 65536;    // 4 x 16*72*2 = 9216 B

  const int qt = blockIdx.x, b = blockIdx.y;
  const int t = threadIdx.x;
  const int wave = t >> 6, lane = t & 63;
  const int lr = lane & 15, lg = lane >> 4;

  // Q fragments in registers (already scaled to exp2 domain)
  short8 qf[4];
  const unsigned short* Qb = Q + ((size_t)b * NS + (size_t)qt * QBLK + wave * 16 + lr) * ND;
#pragma unroll
  for (int kk = 0; kk < 4; ++kk) qf[kk] = *(const short8*)(Qb + kk * 32 + lg * 8);

  const unsigned short* Kb = K + (size_t)b * NS * ND;
  const unsigned short* Vb = Vt + (size_t)b * ND * NS;

  f32x4 oacc[8] = {};
  float m[4] = {-1e30f, -1e30f, -1e30f, -1e30f};
  float l[4] = {0.f, 0.f, 0.f, 0.f};

  auto stage = [&](int buf, int tt) {
    // K tile: 16 KB, 4 wave-issues of 1 KB each; source pre-swizzled
    const char* ksrc = (const char*)(Kb + (size_t)tt * KVBLK * ND);
    char* kdst = ksbase + buf * 16384;
#pragma unroll
    for (int i = 0; i < 4; ++i) {
      int y = (i * 4 + wave) * 1024 + lane * 16;
      int so = y ^ (((y >> 8) & 7) << 4);
      gl_lds16(ksrc + so, kdst + (i * 4 + wave) * 1024);
    }
    // V tile: LDS [128][64], row d = 128 B; gather rows from Vt
    const char* vsrc = (const char*)(Vb + (size_t)tt * KVBLK);
    char* vdst = vsbase + buf * 16384;
#pragma unroll
    for (int i = 0; i < 4; ++i) {
      int y = (i * 4 + wave) * 1024 + lane * 16;
      int d = y >> 7;
      int cx = (y & 127) ^ ((d & 7) << 4);
      gl_lds16(vsrc + (size_t)d * (NS * 2) + cx, vdst + (i * 4 + wave) * 1024);
    }
  };

  stage(0, 0);
  __syncthreads();

  for (int tt = 0; tt < NTILES; ++tt) {
    int buf = tt & 1;
    if (tt + 1 < NTILES) stage(buf ^ 1, tt + 1);
    const char* kb = ksbase + buf * 16384;
    const char* vbuf = vsbase + buf * 16384;

    // ---- QK^T: S[16 x 64] per wave ----
    f32x4 sacc[4] = {};
#pragma unroll
    for (int kk = 0; kk < 4; ++kk) {
#pragma unroll
      for (int nf = 0; nf < 4; ++nf) {
        int n = nf * 16 + lr;
        int ba = (n * 256 + kk * 64 + lg * 16) ^ ((n & 7) << 4);
        short8 bf = *(const short8*)(kb + ba);
        sacc[nf] = MFMA16(qf[kk], bf, sacc[nf]);
      }
    }

    // ---- online softmax (exp2 domain) ----
    float corr[4], pr[4][4];
#pragma unroll
    for (int r = 0; r < 4; ++r) {
      float v0 = fmaxf(fmaxf(sacc[0][r], sacc[1][r]), fmaxf(sacc[2][r], sacc[3][r]));
#pragma unroll
      for (int off = 8; off; off >>= 1) v0 = fmaxf(v0, __shfl_xor(v0, off, 16));
      float mn = fmaxf(m[r], v0);
      corr[r] = exp2f(m[r] - mn);
      m[r] = mn;
    }
#pragma unroll
    for (int r = 0; r < 4; ++r) {
      float s0 = 0.f;
#pragma unroll
      for (int nf = 0; nf < 4; ++nf) {
        float p = exp2f(sacc[nf][r] - m[r]);
        pr[nf][r] = p;
        s0 += p;
      }
#pragma unroll
      for (int off = 8; off; off >>= 1) s0 += __shfl_xor(s0, off, 16);
      l[r] = l[r] * corr[r] + s0;
    }
#pragma unroll
    for (int nf = 0; nf < 8; ++nf)
#pragma unroll
      for (int r = 0; r < 4; ++r) oacc[nf][r] *= corr[r];

    // ---- P -> LDS (bf16), per-wave private, stride 72 (aligned + bank-spread) ----
    unsigned short* pw = (unsigned short*)(psbase + wave * 2304);
#pragma unroll
    for (int nf = 0; nf < 4; ++nf)
#pragma unroll
      for (int r = 0; r < 4; ++r)
        pw[(lg * 4 + r) * 72 + nf * 16 + lr] = f2bf(pr[nf][r]);

    // ---- PV: O[16 x 128] += P[16 x 64] * V[64 x 128] ----
#pragma unroll
    for (int kk2 = 0; kk2 < 2; ++kk2) {
      short8 pa = *(const short8*)((const char*)pw + lr * 144 + kk2 * 64 + lg * 16);
#pragma unroll
      for (int nf = 0; nf < 8; ++nf) {
        int dd = nf * 16 + lr;
        int ba = (dd * 128 + kk2 * 64 + lg * 16) ^ ((dd & 7) << 4);
        short8 vbf = *(const short8*)(vbuf + ba);
        oacc[nf] = MFMA16(pa, vbf, oacc[nf]);
      }
    }
    __syncthreads();
  }

  // ---- epilogue: O / l ----
  float* Ob = Out + ((size_t)b * NS + (size_t)qt * QBLK + wave * 16) * ND;
#pragma unroll
  for (int r = 0; r < 4; ++r) {
    float rl = 1.0f / l[r];
#pragma unroll
    for (int nf = 0; nf < 8; ++nf)
      Ob[(size_t)(lg * 4 + r) * ND + nf * 16 + lr] = oacc[nf][r] * rl;
  }
}

extern "C" void kernel_launch(void* const* d_in, const int* in_sizes, int n_in,
                              void* d_out, int out_size, void* d_ws, size_t ws_size,
                              hipStream_t stream) {
  const float* x  = (const float*)d_in[0];
  const float* Wq = (const float*)d_in[1];
  const float* bq = (const float*)d_in[2];
  const float* Wk = (const float*)d_in[3];
  const float* bk = (const float*)d_in[4];
  const float* Wv = (const float*)d_in[5];
  const float* bv = (const float*)d_in[6];

  unsigned short* Qw  = (unsigned short*)d_ws;                 // 2M elems (4 MB)
  unsigned short* Kw  = Qw + (size_t)NB * NS * ND;             // 4 MB
  unsigned short* Vtw = Kw + (size_t)NB * NS * ND;             // 4 MB (transposed V)

  proj_kernel<<<dim3(NS / 64, NB, 3), 256, 0, stream>>>(
      x, Wq, bq, Wk, bk, Wv, bv, Qw, Kw, Vtw);

  attn_kernel<<<dim3(NS / QBLK, NB), 256, 65536 + 9216, stream>>>(
      Qw, Kw, Vtw, (float*)d_out);
}

// Round 2
// 115.032 us; speedup vs baseline: 1.1510x; 1.1510x over previous
//
#include <hip/hip_runtime.h>
#include <hip/hip_bf16.h>
#include <stdint.h>

#define NB 4
#define NS 4096
#define ND 128
#define KVBLK 64
#define NTILES (NS / KVBLK)

typedef __attribute__((ext_vector_type(8))) short short8;
typedef __attribute__((ext_vector_type(4))) float f32x4;
typedef __attribute__((ext_vector_type(16))) float f32x16;

// log2(e) / sqrt(128): folded into Q so scores come out in exp2 domain.
#define QSCALE 0.12751744f

__device__ __forceinline__ unsigned short f2bf(float f) {
  union { float f; uint32_t u; } v; v.f = f;
  uint32_t r = v.u + 0x7FFFu + ((v.u >> 16) & 1u);   // RNE
  return (unsigned short)(r >> 16);
}

__device__ __forceinline__ void gl_lds16(const void* g, void* l) {
  __builtin_amdgcn_global_load_lds(
      (const __attribute__((address_space(1))) uint32_t*)g,
      (__attribute__((address_space(3))) uint32_t*)l, 16, 0, 0);
}

#define MFMA16(a, b, c) __builtin_amdgcn_mfma_f32_16x16x32_bf16((a), (b), (c), 0, 0, 0)
#define MFMA32(a, b, c) __builtin_amdgcn_mfma_f32_32x32x16_bf16((a), (b), (c), 0, 0, 0)

// ---------------------------------------------------------------------------
// Projection: T = x @ W^T + b  (per blockIdx.z: 0=Q,1=K,2=V)
// Q,K -> bf16 [B][S][D] row-major (Q pre-scaled by log2e/sqrt(D));
// V   -> bf16 [B][D][S] (transposed) so attention's PV reads are contiguous.
// ---------------------------------------------------------------------------
__global__ __launch_bounds__(256) void proj_kernel(
    const float* __restrict__ x,
    const float* __restrict__ Wq, const float* __restrict__ bq,
    const float* __restrict__ Wk, const float* __restrict__ bk,
    const float* __restrict__ Wv, const float* __restrict__ bv,
    unsigned short* __restrict__ Qo, unsigned short* __restrict__ Ko,
    unsigned short* __restrict__ Vt)
{
  __shared__ unsigned short XsTt[128 * 72];
  __shared__ unsigned short Ws[128 * 128];

  const int tile  = blockIdx.x;   // 64 tiles of 64 rows
  const int b     = blockIdx.y;
  const int which = blockIdx.z;

  const float* W    = (which == 0) ? Wq : (which == 1) ? Wk : Wv;
  const float* bias = (which == 0) ? bq : (which == 1) ? bk : bv;

  const int t = threadIdx.x;
  const int wave = t >> 6, lane = t & 63;
  const int lr = lane & 15, lg = lane >> 4;

  const float* xb = x + ((size_t)b * NS + (size_t)tile * 64) * ND;

#pragma unroll
  for (int c = 0; c < 4; ++c) {
    int eo = (c * 256 + t) * 8;
    int row = eo >> 7, col = eo & 127;
    const float4* s = (const float4*)(xb + row * ND + col);
    float4 v0 = s[0], v1 = s[1];
    short8 o;
    o[0] = f2bf(v0.x); o[1] = f2bf(v0.y); o[2] = f2bf(v0.z); o[3] = f2bf(v0.w);
    o[4] = f2bf(v1.x); o[5] = f2bf(v1.y); o[6] = f2bf(v1.z); o[7] = f2bf(v1.w);
    int ba = (row * 256 + col * 2) ^ ((row & 7) << 4);
    *(short8*)((char*)XsTt + ba) = o;
  }
#pragma unroll
  for (int c = 0; c < 8; ++c) {
    int eo = (c * 256 + t) * 8;
    int row = eo >> 7, col = eo & 127;
    const float4* s = (const float4*)(W + row * ND + col);
    float4 v0 = s[0], v1 = s[1];
    short8 o;
    o[0] = f2bf(v0.x); o[1] = f2bf(v0.y); o[2] = f2bf(v0.z); o[3] = f2bf(v0.w);
    o[4] = f2bf(v1.x); o[5] = f2bf(v1.y); o[6] = f2bf(v1.z); o[7] = f2bf(v1.w);
    int ba = (row * 256 + col * 2) ^ ((row & 7) << 4);
    *(short8*)((char*)Ws + ba) = o;
  }
  __syncthreads();

  short8 af[4];
#pragma unroll
  for (int kk = 0; kk < 4; ++kk) {
    int row = wave * 16 + lr;
    int ba = (row * 256 + kk * 64 + lg * 16) ^ ((row & 7) << 4);
    af[kk] = *(const short8*)((const char*)XsTt + ba);
  }
  f32x4 acc[8] = {};
#pragma unroll
  for (int kk = 0; kk < 4; ++kk) {
#pragma unroll
    for (int nf = 0; nf < 8; ++nf) {
      int n = nf * 16 + lr;
      int ba = (n * 256 + kk * 64 + lg * 16) ^ ((n & 7) << 4);
      short8 bf = *(const short8*)((const char*)Ws + ba);
      acc[nf] = MFMA16(af[kk], bf, acc[nf]);
    }
  }

  if (which < 2) {
    unsigned short* Out = (which == 0) ? Qo : Ko;
    const float sc = (which == 0) ? QSCALE : 1.0f;
#pragma unroll
    for (int nf = 0; nf < 8; ++nf) {
      float bb = bias[nf * 16 + lr];
#pragma unroll
      for (int r = 0; r < 4; ++r) {
        float v = (acc[nf][r] + bb) * sc;
        int row = tile * 64 + wave * 16 + lg * 4 + r;
        Out[((size_t)b * NS + row) * ND + nf * 16 + lr] = f2bf(v);
      }
    }
  } else {
    __syncthreads();
    unsigned short* Tt = XsTt;    // [128][72]
#pragma unroll
    for (int nf = 0; nf < 8; ++nf) {
      float bb = bias[nf * 16 + lr];
#pragma unroll
      for (int r = 0; r < 4; ++r) {
        int e = nf * 16 + lr;
        int sl = wave * 16 + lg * 4 + r;
        Tt[e * 72 + sl] = f2bf(acc[nf][r] + bb);
      }
    }
    __syncthreads();
    int e = t >> 1, off = (t & 1) * 32;
    const short8* src = (const short8*)(Tt + e * 72 + off);
    short8* dst = (short8*)(Vt + ((size_t)b * ND + e) * NS + (size_t)tile * 64 + off);
#pragma unroll
    for (int i = 0; i < 4; ++i) dst[i] = src[i];
  }
}

// ---------------------------------------------------------------------------
// Flash attention, m214-style: 4 waves x 32 q-rows, 32x32x16 MFMA,
// swapped QK^T (D[kv][q]) -> lane-local softmax; swapped PV (D[d][q]).
// Split-KV: each block does one chunk; writes unnormalized O^T + m,l.
// ---------------------------------------------------------------------------
__global__ __launch_bounds__(256, 2) void attn_kernel(
    const unsigned short* __restrict__ Q, const unsigned short* __restrict__ K,
    const unsigned short* __restrict__ Vt, float* __restrict__ OP,
    float* __restrict__ Mp, float* __restrict__ Lp, int nchunk, int ntpc)
{
  extern __shared__ char smem[];   // 2 bufs x (16KB K + 16KB V) = 64KB

  // decode flat block id with XCD-aware grouping: blocks sharing (b,chunk)
  // land on the same XCD so the 512KB K/V chunk stays L2-resident.
  const int Lid = blockIdx.x;
  const int ngroups = NB * nchunk;
  int g, qt;
  if ((ngroups & 7) == 0) {
    int xcd = Lid & 7, s2 = Lid >> 3;
    g = xcd * (ngroups >> 3) + (s2 >> 5);
    qt = s2 & 31;
  } else { g = Lid >> 5; qt = Lid & 31; }
  const int b = g & (NB - 1), c = g >> 2;

  const int t = threadIdx.x, wave = t >> 6, lane = t & 63;
  const int lq = lane & 31, hi = lane >> 5;

  // Q fragments: q = lane&31, d = kt*16 + hi*8 + j  (B-operand of QK^T)
  short8 qf[8];
  const unsigned short* Qb =
      Q + ((size_t)b * NS + (size_t)qt * 128 + wave * 32 + lq) * ND;
#pragma unroll
  for (int kt = 0; kt < 8; ++kt) qf[kt] = *(const short8*)(Qb + kt * 16 + hi * 8);

  const unsigned short* Kc =
      K + ((size_t)b * NS + (size_t)c * ntpc * KVBLK) * ND;
  const unsigned short* Vb = Vt + (size_t)b * ND * NS;
  const size_t vcol0 = (size_t)c * ntpc * KVBLK;

  auto stage = [&](int buf, int tt) {
    const char* ksrc = (const char*)(Kc + (size_t)tt * KVBLK * ND);
    char* kdst = smem + buf * 32768;
#pragma unroll
    for (int i = 0; i < 4; ++i) {
      int y = (i * 4 + wave) * 1024 + lane * 16;
      int so = y ^ (((y >> 8) & 7) << 4);
      gl_lds16(ksrc + so, kdst + (i * 4 + wave) * 1024);
    }
    const char* vsrc = (const char*)(Vb + vcol0 + (size_t)tt * KVBLK);
    char* vdst = kdst + 16384;
#pragma unroll
    for (int i = 0; i < 4; ++i) {
      int y = (i * 4 + wave) * 1024 + lane * 16;
      int d = y >> 7;
      int cx = (y & 127) ^ ((d & 7) << 4);
      gl_lds16(vsrc + (size_t)d * (NS * 2) + cx, vdst + (i * 4 + wave) * 1024);
    }
  };

  f32x16 oacc[4] = {};
  float m = -1e30f, l = 0.f;

  stage(0, 0);
  __syncthreads();

  for (int tt = 0; tt < ntpc; ++tt) {
    int buf = tt & 1;
    if (tt + 1 < ntpc) stage(buf ^ 1, tt + 1);
    const char* kb = smem + buf * 32768;
    const char* vb = kb + 16384;

    // ---- QK^T (swapped): s[mt] = K[mt*32..][:] . Q  -> D[kv][q] ----
    f32x16 s0 = {}, s1 = {};
#pragma unroll
    for (int kt = 0; kt < 8; ++kt) {
      int co = (kt * 32 + hi * 16) ^ ((lq & 7) << 4);
      short8 k0 = *(const short8*)(kb + lq * 256 + co);
      short8 k1 = *(const short8*)(kb + (32 + lq) * 256 + co);
      s0 = MFMA32(k0, qf[kt], s0);
      s1 = MFMA32(k1, qf[kt], s1);
    }

    // ---- lane-local online softmax (q = lane&31; kv rows in regs) ----
    float px = fmaxf(s0[0], s1[0]);
#pragma unroll
    for (int r = 1; r < 16; ++r) px = fmaxf(px, fmaxf(s0[r], s1[r]));
    px = fmaxf(px, __shfl_xor(px, 32, 64));
    float mn = fmaxf(m, px);
    float corr = exp2f(m - mn);
    m = mn;
    float p0[16], p1[16];
    float ssum = 0.f;
#pragma unroll
    for (int r = 0; r < 16; ++r) {
      p0[r] = exp2f(s0[r] - m);
      p1[r] = exp2f(s1[r] - m);
      ssum += p0[r] + p1[r];
    }
    ssum += __shfl_xor(ssum, 32, 64);
    l = l * corr + ssum;
#pragma unroll
    for (int dt = 0; dt < 4; ++dt)
#pragma unroll
      for (int r = 0; r < 16; ++r) oacc[dt][r] *= corr;

    // ---- pack P to bf16 pairs; exchange halves; build PV B-frags ----
    // reg r holds kv_local = (r&3) + 8*(r>>2) + 4*hi  (within each 32-blk)
    uint32_t pk0[8], pk1[8];
#pragma unroll
    for (int i = 0; i < 8; ++i) {
      pk0[i] = (uint32_t)f2bf(p0[2 * i]) | ((uint32_t)f2bf(p0[2 * i + 1]) << 16);
      pk1[i] = (uint32_t)f2bf(p1[2 * i]) | ((uint32_t)f2bf(p1[2 * i + 1]) << 16);
    }
    short8 pfrag[4];   // [mt*2 + kt2]: B[k=kv16][n=q], k = hi*8 + j
#pragma unroll
    for (int mt = 0; mt < 2; ++mt) {
      const uint32_t* pk = mt ? pk1 : pk0;
#pragma unroll
      for (int kt2 = 0; kt2 < 2; ++kt2) {
        uint32_t a0 = pk[4 * kt2 + 0], a1 = pk[4 * kt2 + 1];
        uint32_t a2 = pk[4 * kt2 + 2], a3 = pk[4 * kt2 + 3];
        uint32_t sA = hi ? a0 : a2;
        uint32_t sB = hi ? a1 : a3;
        uint32_t rA = (uint32_t)__shfl_xor((int)sA, 32, 64);
        uint32_t rB = (uint32_t)__shfl_xor((int)sB, 32, 64);
        union { uint32_t u[4]; short8 s; } pf;
        pf.u[0] = hi ? rA : a0;
        pf.u[1] = hi ? rB : a1;
        pf.u[2] = hi ? a2 : rA;
        pf.u[3] = hi ? a3 : rB;
        pfrag[mt * 2 + kt2] = pf.s;
      }
    }

    // ---- PV (swapped): oacc[dt] += V^T[dt] . P^T  -> D[d][q] ----
#pragma unroll
    for (int dt = 0; dt < 4; ++dt) {
      int rowb = (dt * 32 + lq) * 128;
      int sw = (lq & 7) << 4;
#pragma unroll
      for (int mt = 0; mt < 2; ++mt)
#pragma unroll
        for (int kt2 = 0; kt2 < 2; ++kt2) {
          int co = (mt * 64 + kt2 * 32 + hi * 16) ^ sw;
          short8 vf = *(const short8*)(vb + rowb + co);
          oacc[dt] = MFMA32(vf, pfrag[mt * 2 + kt2], oacc[dt]);
        }
    }
    __syncthreads();
  }

  // ---- epilogue: unnormalized O^T partial [g][d][s], plus m,l ----
  const size_t qg = (size_t)qt * 128 + wave * 32 + lq;
  float* OPb = OP + ((size_t)(c * NB + b) * ND) * NS + qg;
#pragma unroll
  for (int dt = 0; dt < 4; ++dt)
#pragma unroll
    for (int r = 0; r < 16; ++r) {
      int d = dt * 32 + (r & 3) + 8 * (r >> 2) + 4 * hi;
      OPb[(size_t)d * NS] = oacc[dt][r];
    }
  if (hi == 0) {
    Mp[(size_t)(c * NB + b) * NS + qg] = m;
    Lp[(size_t)(c * NB + b) * NS + qg] = l;
  }
}

// ---------------------------------------------------------------------------
// Combine: O[b][q][d] = sum_c exp2(m_c-M) O_c[d][q] / sum_c exp2(m_c-M) l_c
// (also does the final d<->q transpose via LDS; handles nchunk==1.)
// ---------------------------------------------------------------------------
__global__ __launch_bounds__(256) void combine_kernel(
    const float* __restrict__ OP, const float* __restrict__ Mp,
    const float* __restrict__ Lp, float* __restrict__ Out, int nchunk)
{
  __shared__ float wn[4][64];
  __shared__ float LT[64][129];

  const int qtile = blockIdx.x, b = blockIdx.y;
  const int t = threadIdx.x;

  if (t < 64) {
    size_t qg = (size_t)qtile * 64 + t;
    float wloc[4];
    float mx = -1e30f;
    for (int cc = 0; cc < nchunk; ++cc)
      mx = fmaxf(mx, Mp[(size_t)(cc * NB + b) * NS + qg]);
    float Lt = 0.f;
    for (int cc = 0; cc < nchunk; ++cc) {
      float w = exp2f(Mp[(size_t)(cc * NB + b) * NS + qg] - mx);
      Lt += w * Lp[(size_t)(cc * NB + b) * NS + qg];
      wloc[cc] = w;
    }
    float inv = 1.0f / Lt;
    for (int cc = 0; cc < nchunk; ++cc) wn[cc][t] = wloc[cc] * inv;
  }
  __syncthreads();

  const int q = t & 63, dl = t >> 6;
#pragma unroll 4
  for (int pass = 0; pass < 32; ++pass) {
    int d = pass * 4 + dl;
    float a = 0.f;
    for (int cc = 0; cc < nchunk; ++cc)
      a += wn[cc][q] *
           OP[((size_t)(cc * NB + b) * ND + d) * NS + (size_t)qtile * 64 + q];
    LT[q][d] = a;
  }
  __syncthreads();

  const int d2 = t & 127, qh = t >> 7;
  float* Ob = Out + ((size_t)b * NS + (size_t)qtile * 64) * ND;
#pragma unroll 4
  for (int pass = 0; pass < 32; ++pass) {
    int qq = pass * 2 + qh;
    Ob[(size_t)qq * ND + d2] = LT[qq][d2];
  }
}

extern "C" void kernel_launch(void* const* d_in, const int* in_sizes, int n_in,
                              void* d_out, int out_size, void* d_ws, size_t ws_size,
                              hipStream_t stream) {
  const float* x  = (const float*)d_in[0];
  const float* Wq = (const float*)d_in[1];
  const float* bq = (const float*)d_in[2];
  const float* Wk = (const float*)d_in[3];
  const float* bk = (const float*)d_in[4];
  const float* Wv = (const float*)d_in[5];
  const float* bv = (const float*)d_in[6];

  const size_t elems = (size_t)NB * NS * ND;
  unsigned short* Qw  = (unsigned short*)d_ws;
  unsigned short* Kw  = Qw + elems;
  unsigned short* Vtw = Kw + elems;

  // pick split-KV factor that fits the workspace
  const size_t qkv_bytes = 3 * elems * 2;
  int nchunk = 4;
  while (nchunk > 1) {
    size_t need = qkv_bytes + (size_t)nchunk * (elems * 4 + 2 * (size_t)NB * NS * 4);
    if (need <= ws_size) break;
    nchunk >>= 1;
  }
  float* OPw = (float*)((char*)d_ws + qkv_bytes);
  float* Mpw = (float*)((char*)OPw + (size_t)nchunk * elems * 4);
  float* Lpw = Mpw + (size_t)nchunk * NB * NS;

  proj_kernel<<<dim3(NS / 64, NB, 3), 256, 0, stream>>>(
      x, Wq, bq, Wk, bk, Wv, bv, Qw, Kw, Vtw);

  attn_kernel<<<dim3(32 * NB * nchunk), 256, 65536, stream>>>(
      Qw, Kw, Vtw, OPw, Mpw, Lpw, nchunk, NTILES / nchunk);

  combine_kernel<<<dim3(NS / 64, NB), 256, 0, stream>>>(
      OPw, Mpw, Lpw, (float*)d_out, nchunk);
}

// Round 3
// 109.093 us; speedup vs baseline: 1.2137x; 1.0544x over previous
//
#include <hip/hip_runtime.h>
#include <hip/hip_bf16.h>
#include <stdint.h>

#define NB 4
#define NS 4096
#define ND 128
#define KVBLK 64
#define NTILES (NS / KVBLK)

typedef __attribute__((ext_vector_type(8))) short short8;
typedef __attribute__((ext_vector_type(4))) float f32x4;
typedef __attribute__((ext_vector_type(16))) float f32x16;
typedef __attribute__((ext_vector_type(2))) int i32x2;

// log2(e) / sqrt(128): folded into Q so scores come out in exp2 domain.
#define QSCALE 0.12751744f

__device__ __forceinline__ unsigned short f2bfu(float f) {
  __hip_bfloat16 h = __float2bfloat16(f);   // RNE; pairs fuse to v_cvt_pk_bf16_f32
  union { __hip_bfloat16 h; unsigned short u; } c; c.h = h; return c.u;
}
__device__ __forceinline__ uint32_t pack2bf(float lo, float hi) {
  return (uint32_t)f2bfu(lo) | ((uint32_t)f2bfu(hi) << 16);
}

__device__ __forceinline__ void gl_lds16(const void* g, void* l) {
  __builtin_amdgcn_global_load_lds(
      (const __attribute__((address_space(1))) uint32_t*)g,
      (__attribute__((address_space(3))) uint32_t*)l, 16, 0, 0);
}

#define MFMA16(a, b, c) __builtin_amdgcn_mfma_f32_16x16x32_bf16((a), (b), (c), 0, 0, 0)
#define MFMA32(a, b, c) __builtin_amdgcn_mfma_f32_32x32x16_bf16((a), (b), (c), 0, 0, 0)

// half-swap: lo' = {lo.lo, hi.lo-shifted}, hi' = {lo.hi-shifted, hi.hi}
#if __has_builtin(__builtin_amdgcn_permlane32_swap)
#define PLSWAP(lo_, hi_)                                                        \
  { i32x2 r_ = __builtin_amdgcn_permlane32_swap((int)(lo_), (int)(hi_), false,  \
                                                false);                         \
    lo_ = (uint32_t)r_[0]; hi_ = (uint32_t)r_[1]; }
#else
#define PLSWAP(lo_, hi_)                                                        \
  { uint32_t sA_ = hi ? (lo_) : (hi_);                                          \
    uint32_t rA_ = (uint32_t)__shfl_xor((int)sA_, 32, 64);                      \
    uint32_t nl_ = hi ? rA_ : (lo_);                                            \
    uint32_t nh_ = hi ? (hi_) : rA_;                                            \
    lo_ = nl_; hi_ = nh_; }
#endif

// ---------------------------------------------------------------------------
// Preconvert x and W to bf16 (linear row-major) so proj can gl_lds-stage.
// ---------------------------------------------------------------------------
__global__ __launch_bounds__(512) void preconv_kernel(
    const float* __restrict__ x,
    const float* __restrict__ Wq, const float* __restrict__ Wk,
    const float* __restrict__ Wv,
    unsigned short* __restrict__ xb, unsigned short* __restrict__ Wb)
{
  const size_t xg8 = (size_t)NB * NS * ND / 8;   // 262144
  size_t i = (size_t)blockIdx.x * 512 + threadIdx.x;
  const float* src; unsigned short* dst; size_t off;
  if (i < xg8) { src = x; dst = xb; off = i * 8; }
  else {
    size_t j = i - xg8;                          // < 6144
    int which = (int)(j / 2048);
    src = which == 0 ? Wq : which == 1 ? Wk : Wv;
    dst = Wb;
    off = j * 8;                                 // dst offset global
    src = src - (size_t)which * 16384;           // so src+off lands right
  }
  float4 a = *(const float4*)(src + off), b2 = *(const float4*)(src + off + 4);
  short8 o;
  o[0] = (short)f2bfu(a.x);  o[1] = (short)f2bfu(a.y);
  o[2] = (short)f2bfu(a.z);  o[3] = (short)f2bfu(a.w);
  o[4] = (short)f2bfu(b2.x); o[5] = (short)f2bfu(b2.y);
  o[6] = (short)f2bfu(b2.z); o[7] = (short)f2bfu(b2.w);
  *(short8*)(dst + off) = o;
}

// ---------------------------------------------------------------------------
// Projection (bf16 in): T = x @ W^T + b  (blockIdx.z: 0=Q,1=K,2=V)
// ---------------------------------------------------------------------------
__global__ __launch_bounds__(256) void proj_kernel(
    const unsigned short* __restrict__ xb, const unsigned short* __restrict__ Wb,
    const float* __restrict__ bq, const float* __restrict__ bk,
    const float* __restrict__ bv,
    unsigned short* __restrict__ Qo, unsigned short* __restrict__ Ko,
    unsigned short* __restrict__ Vt)
{
  __shared__ unsigned short Xs[64 * 128];    // 16 KB
  __shared__ unsigned short Ws[128 * 128];   // 32 KB (overlaid as Tt for V)

  const int tile = blockIdx.x, b = blockIdx.y, which = blockIdx.z;
  const float* bias = which == 0 ? bq : which == 1 ? bk : bv;
  const int t = threadIdx.x, wave = t >> 6, lane = t & 63;
  const int lr = lane & 15, lg = lane >> 4;

  const char* xsrc = (const char*)(xb + ((size_t)b * NS + (size_t)tile * 64) * ND);
#pragma unroll
  for (int i = wave; i < 16; i += 4) {
    int y = i * 1024 + lane * 16;
    int so = y ^ (((y >> 8) & 7) << 4);
    gl_lds16(xsrc + so, (char*)Xs + y);
  }
  const char* wsrc = (const char*)(Wb + (size_t)which * 16384);
#pragma unroll
  for (int i = wave; i < 32; i += 4) {
    int y = i * 1024 + lane * 16;
    int so = y ^ (((y >> 8) & 7) << 4);
    gl_lds16(wsrc + so, (char*)Ws + y);
  }
  __syncthreads();

  short8 af[4];
#pragma unroll
  for (int kk = 0; kk < 4; ++kk) {
    int row = wave * 16 + lr;
    int ba = (row * 256 + kk * 64 + lg * 16) ^ ((row & 7) << 4);
    af[kk] = *(const short8*)((const char*)Xs + ba);
  }
  f32x4 acc[8] = {};
#pragma unroll
  for (int kk = 0; kk < 4; ++kk) {
#pragma unroll
    for (int nf = 0; nf < 8; ++nf) {
      int n = nf * 16 + lr;
      int ba = (n * 256 + kk * 64 + lg * 16) ^ ((n & 7) << 4);
      short8 bf = *(const short8*)((const char*)Ws + ba);
      acc[nf] = MFMA16(af[kk], bf, acc[nf]);
    }
  }

  if (which < 2) {
    unsigned short* Out = (which == 0) ? Qo : Ko;
    const float sc = (which == 0) ? QSCALE : 1.0f;
#pragma unroll
    for (int nf = 0; nf < 8; ++nf) {
      float bb = bias[nf * 16 + lr];
#pragma unroll
      for (int r = 0; r < 4; ++r) {
        float v = (acc[nf][r] + bb) * sc;
        int row = tile * 64 + wave * 16 + lg * 4 + r;
        Out[((size_t)b * NS + row) * ND + nf * 16 + lr] = f2bfu(v);
      }
    }
  } else {
    __syncthreads();                 // all MFMA reads of Ws done
    unsigned short* Tt = Ws;         // [128][72] overlay (18 KB <= 32 KB)
#pragma unroll
    for (int nf = 0; nf < 8; ++nf) {
      float bb = bias[nf * 16 + lr];
#pragma unroll
      for (int r = 0; r < 4; ++r) {
        int e = nf * 16 + lr;
        int sl = wave * 16 + lg * 4 + r;
        Tt[e * 72 + sl] = f2bfu(acc[nf][r] + bb);
      }
    }
    __syncthreads();
    int e = t >> 1, off = (t & 1) * 32;
    const short8* src = (const short8*)(Tt + e * 72 + off);
    short8* dst = (short8*)(Vt + ((size_t)b * ND + e) * NS + (size_t)tile * 64 + off);
#pragma unroll
    for (int i = 0; i < 4; ++i) dst[i] = src[i];
  }
}

// ---------------------------------------------------------------------------
// Flash attention: nwaves x 32 q-rows, 32x32x16 MFMA, swapped operands,
// lane-local softmax + defer-max, permlane P exchange, split-KV partials.
// ---------------------------------------------------------------------------
__global__ __launch_bounds__(512, 4) void attn_kernel(
    const unsigned short* __restrict__ Q, const unsigned short* __restrict__ K,
    const unsigned short* __restrict__ Vt, float* __restrict__ OP,
    float* __restrict__ Mp, float* __restrict__ Lp,
    int nchunk, int ntpc, int qts_shift)
{
  extern __shared__ char smem[];   // 2 bufs x (16KB K + 16KB V) = 64 KB
  const int nwaves = blockDim.x >> 6;
  const int qtm = 1 << qts_shift;

  const int Lid = blockIdx.x;
  int g, qt;
  if (((NB * nchunk) & 7) == 0) {
    int xcd = Lid & 7, s2 = Lid >> 3;
    qt = s2 & (qtm - 1);
    g = xcd * ((NB * nchunk) >> 3) + (s2 >> qts_shift);
  } else { qt = Lid & (qtm - 1); g = Lid >> qts_shift; }
  const int b = g & (NB - 1), c = g >> 2;

  const int t = threadIdx.x, wave = t >> 6, lane = t & 63;
  const int lq = lane & 31, hi = lane >> 5;

  const int qrow = qt * (nwaves * 32) + wave * 32 + lq;
  short8 qf[8];
  const unsigned short* Qb = Q + ((size_t)b * NS + qrow) * ND;
#pragma unroll
  for (int kt = 0; kt < 8; ++kt) qf[kt] = *(const short8*)(Qb + kt * 16 + hi * 8);

  const unsigned short* Kc = K + ((size_t)b * NS + (size_t)c * ntpc * KVBLK) * ND;
  const unsigned short* Vb = Vt + (size_t)b * ND * NS;
  const size_t vcol0 = (size_t)c * ntpc * KVBLK;

  auto stage = [&](int buf, int tt) {
    const char* ksrc = (const char*)(Kc + (size_t)tt * KVBLK * ND);
    char* kdst = smem + buf * 32768;
    for (int i = wave; i < 16; i += nwaves) {
      int y = i * 1024 + lane * 16;
      int so = y ^ (((y >> 8) & 7) << 4);
      gl_lds16(ksrc + so, kdst + y);
    }
    const char* vsrc = (const char*)(Vb + vcol0 + (size_t)tt * KVBLK);
    char* vdst = kdst + 16384;
    for (int i = wave; i < 16; i += nwaves) {
      int y = i * 1024 + lane * 16;
      int d = y >> 7;
      int cx = (y & 127) ^ ((d & 7) << 4);
      gl_lds16(vsrc + (size_t)d * (NS * 2) + cx, vdst + y);
    }
  };

  f32x16 oacc[4] = {};
  float m = -1e30f, l = 0.f;

  stage(0, 0);
  __syncthreads();

  for (int tt = 0; tt < ntpc; ++tt) {
    int buf = tt & 1;
    if (tt + 1 < ntpc) stage(buf ^ 1, tt + 1);
    const char* kb = smem + buf * 32768;
    const char* vb = kb + 16384;

    // ---- QK^T (swapped): D[kv][q] ----
    f32x16 s0 = {}, s1 = {};
    __builtin_amdgcn_s_setprio(1);
#pragma unroll
    for (int kt = 0; kt < 8; ++kt) {
      int co = (kt * 32 + hi * 16) ^ ((lq & 7) << 4);
      short8 k0 = *(const short8*)(kb + lq * 256 + co);
      short8 k1 = *(const short8*)(kb + (32 + lq) * 256 + co);
      s0 = MFMA32(k0, qf[kt], s0);
      s1 = MFMA32(k1, qf[kt], s1);
    }
    __builtin_amdgcn_s_setprio(0);

    // ---- lane-local online softmax with defer-max (THR=8) ----
    float x0 = fmaxf(s0[0], s1[0]), x1 = fmaxf(s0[1], s1[1]);
    float x2 = fmaxf(s0[2], s1[2]), x3 = fmaxf(s0[3], s1[3]);
#pragma unroll
    for (int r = 4; r < 16; r += 4) {
      x0 = fmaxf(x0, fmaxf(s0[r], s1[r]));
      x1 = fmaxf(x1, fmaxf(s0[r + 1], s1[r + 1]));
      x2 = fmaxf(x2, fmaxf(s0[r + 2], s1[r + 2]));
      x3 = fmaxf(x3, fmaxf(s0[r + 3], s1[r + 3]));
    }
    float px = fmaxf(fmaxf(x0, x1), fmaxf(x2, x3));
    px = fmaxf(px, __shfl_xor(px, 32, 64));
    if (__any(px > m + 8.f)) {
      float mn = fmaxf(m, px);
      float corr = exp2f(m - mn);
      m = mn;
      l *= corr;
#pragma unroll
      for (int dt = 0; dt < 4; ++dt)
#pragma unroll
        for (int r = 0; r < 16; ++r) oacc[dt][r] *= corr;
    }

    float p0[16], p1[16];
    float u0 = 0.f, u1 = 0.f, u2 = 0.f, u3 = 0.f;
#pragma unroll
    for (int r = 0; r < 16; r += 4) {
      p0[r] = exp2f(s0[r] - m);     p1[r] = exp2f(s1[r] - m);
      p0[r+1] = exp2f(s0[r+1] - m); p1[r+1] = exp2f(s1[r+1] - m);
      p0[r+2] = exp2f(s0[r+2] - m); p1[r+2] = exp2f(s1[r+2] - m);
      p0[r+3] = exp2f(s0[r+3] - m); p1[r+3] = exp2f(s1[r+3] - m);
      u0 += p0[r] + p1[r];       u1 += p0[r+1] + p1[r+1];
      u2 += p0[r+2] + p1[r+2];   u3 += p0[r+3] + p1[r+3];
    }
    float ssum = (u0 + u1) + (u2 + u3);
    ssum += __shfl_xor(ssum, 32, 64);
    l += ssum;

    // ---- pack P -> bf16 pairs; permlane half-exchange; PV B-frags ----
    uint32_t pk0[8], pk1[8];
#pragma unroll
    for (int i = 0; i < 8; ++i) {
      pk0[i] = pack2bf(p0[2 * i], p0[2 * i + 1]);
      pk1[i] = pack2bf(p1[2 * i], p1[2 * i + 1]);
    }
    short8 pfrag[4];
#pragma unroll
    for (int mt = 0; mt < 2; ++mt) {
      const uint32_t* pk = mt ? pk1 : pk0;
#pragma unroll
      for (int kt2 = 0; kt2 < 2; ++kt2) {
        uint32_t e0 = pk[4 * kt2 + 0], e1 = pk[4 * kt2 + 1];
        uint32_t e2 = pk[4 * kt2 + 2], e3 = pk[4 * kt2 + 3];
        PLSWAP(e0, e2);
        PLSWAP(e1, e3);
        union { uint32_t u[4]; short8 s; } pf;
        pf.u[0] = e0; pf.u[1] = e1; pf.u[2] = e2; pf.u[3] = e3;
        pfrag[mt * 2 + kt2] = pf.s;
      }
    }

    // ---- PV (swapped): oacc[dt] += V^T[dt] . P^T -> D[d][q] ----
    __builtin_amdgcn_s_setprio(1);
#pragma unroll
    for (int dt = 0; dt < 4; ++dt) {
      int rowb = (dt * 32 + lq) * 128;
      int sw = (lq & 7) << 4;
#pragma unroll
      for (int mt = 0; mt < 2; ++mt)
#pragma unroll
        for (int kt2 = 0; kt2 < 2; ++kt2) {
          int co = (mt * 64 + kt2 * 32 + hi * 16) ^ sw;
          short8 vf = *(const short8*)(vb + rowb + co);
          oacc[dt] = MFMA32(vf, pfrag[mt * 2 + kt2], oacc[dt]);
        }
    }
    __builtin_amdgcn_s_setprio(0);
    __syncthreads();
  }

  // ---- epilogue: unnormalized O^T partial [g][d][s], plus m,l ----
  const size_t qg = (size_t)qrow;
  float* OPb = OP + ((size_t)(c * NB + b) * ND) * NS + qg;
#pragma unroll
  for (int dt = 0; dt < 4; ++dt)
#pragma unroll
    for (int r = 0; r < 16; ++r) {
      int d = dt * 32 + (r & 3) + 8 * (r >> 2) + 4 * hi;
      OPb[(size_t)d * NS] = oacc[dt][r];
    }
  if (hi == 0) {
    Mp[(size_t)(c * NB + b) * NS + qg] = m;
    Lp[(size_t)(c * NB + b) * NS + qg] = l;
  }
}

// ---------------------------------------------------------------------------
// Combine partials across chunks + transpose back to [b][q][d].
// ---------------------------------------------------------------------------
__global__ __launch_bounds__(256) void combine_kernel(
    const float* __restrict__ OP, const float* __restrict__ Mp,
    const float* __restrict__ Lp, float* __restrict__ Out, int nchunk)
{
  __shared__ float wn[8][64];
  __shared__ float LT[64][129];

  const int qtile = blockIdx.x, b = blockIdx.y;
  const int t = threadIdx.x;

  if (t < 64) {
    size_t qg = (size_t)qtile * 64 + t;
    float wloc[8];
    float mx = -1e30f;
    for (int cc = 0; cc < nchunk; ++cc)
      mx = fmaxf(mx, Mp[(size_t)(cc * NB + b) * NS + qg]);
    float Lt = 0.f;
    for (int cc = 0; cc < nchunk; ++cc) {
      float w = exp2f(Mp[(size_t)(cc * NB + b) * NS + qg] - mx);
      Lt += w * Lp[(size_t)(cc * NB + b) * NS + qg];
      wloc[cc] = w;
    }
    float inv = 1.0f / Lt;
    for (int cc = 0; cc < nchunk; ++cc) wn[cc][t] = wloc[cc] * inv;
  }
  __syncthreads();

  const int q = t & 63, dl = t >> 6;
#pragma unroll 4
  for (int pass = 0; pass < 32; ++pass) {
    int d = pass * 4 + dl;
    float a = 0.f;
    for (int cc = 0; cc < nchunk; ++cc)
      a += wn[cc][q] *
           OP[((size_t)(cc * NB + b) * ND + d) * NS + (size_t)qtile * 64 + q];
    LT[q][d] = a;
  }
  __syncthreads();

  const int d2 = t & 127, qh = t >> 7;
  float* Ob = Out + ((size_t)b * NS + (size_t)qtile * 64) * ND;
#pragma unroll 4
  for (int pass = 0; pass < 32; ++pass) {
    int qq = pass * 2 + qh;
    Ob[(size_t)qq * ND + d2] = LT[qq][d2];
  }
}

extern "C" void kernel_launch(void* const* d_in, const int* in_sizes, int n_in,
                              void* d_out, int out_size, void* d_ws, size_t ws_size,
                              hipStream_t stream) {
  const float* x  = (const float*)d_in[0];
  const float* Wq = (const float*)d_in[1];
  const float* bq = (const float*)d_in[2];
  const float* Wk = (const float*)d_in[3];
  const float* bk = (const float*)d_in[4];
  const float* Wv = (const float*)d_in[5];
  const float* bv = (const float*)d_in[6];

  const size_t elems = (size_t)NB * NS * ND;
  char* base = (char*)d_ws;
  unsigned short* Qw  = (unsigned short*)base;
  unsigned short* Kw  = Qw + elems;
  unsigned short* Vtw = Kw + elems;
  char* region2 = base + 3 * elems * 2;            // 12 MB offset

  // split-KV factor: largest of {8,4,2,1} fitting ws.
  int nchunk = 8;
  while (nchunk > 1) {
    size_t need = 3 * elems * 2 +
                  (size_t)nchunk * (elems * 4 + 2 * (size_t)NB * NS * 4);
    if (need <= ws_size) break;
    nchunk >>= 1;
  }

  // xb16/Wb16 alias the OP region (proj finishes before attn writes OP).
  unsigned short* xb16 = (unsigned short*)region2;
  unsigned short* Wb16 = xb16 + elems;
  float* OPw = (float*)region2;
  float* Mpw = (float*)(region2 + (size_t)nchunk * elems * 4);
  float* Lpw = Mpw + (size_t)nchunk * NB * NS;

  preconv_kernel<<<dim3(524), 512, 0, stream>>>(x, Wq, Wk, Wv, xb16, Wb16);

  proj_kernel<<<dim3(NS / 64, NB, 3), 256, 0, stream>>>(
      xb16, Wb16, bq, bk, bv, Qw, Kw, Vtw);

  const int threads = (nchunk >= 8) ? 512 : 256;
  const int qts_shift = (nchunk >= 8) ? 4 : 5;
  const int qtm = 1 << qts_shift;
  const int blocks = qtm * NB * nchunk;
  attn_kernel<<<dim3(blocks), threads, 65536, stream>>>(
      Qw, Kw, Vtw, OPw, Mpw, Lpw, nchunk, NTILES / nchunk, qts_shift);

  combine_kernel<<<dim3(NS / 64, NB), 256, 0, stream>>>(
      OPw, Mpw, Lpw, (float*)d_out, nchunk);
}